// Round 1
// baseline (317.841 us; speedup 1.0000x reference)
//
#include <hip/hip_runtime.h>
#include <hip/hip_bf16.h>
#include <stdint.h>

#define BATCH 2
#define SEQ 2048
#define DMODEL 1024
#define NHEADS 16
#define HDIM 64
#define MROWS (BATCH*SEQ)   /* 4096 */
#define N3 (3*DMODEL)       /* 3072 */

typedef __attribute__((ext_vector_type(8))) __bf16 bf16x8;
typedef __attribute__((ext_vector_type(4))) float f32x4;

__device__ __forceinline__ ushort f2b(float f) {
  uint32_t u = __builtin_bit_cast(uint32_t, f);
  uint32_t r = (u + 0x7FFFu + ((u >> 16) & 1u)) >> 16;
  return (ushort)r;
}
__device__ __forceinline__ float b2f(ushort h) {
  return __builtin_bit_cast(float, (uint32_t)h << 16);
}

/* ---------------- f32 -> bf16 convert, 4 elems/thread ---------------- */
__global__ void f2b_kernel(const float* __restrict__ in, ushort* __restrict__ out, int n4) {
  int i = blockIdx.x * blockDim.x + threadIdx.x;
  if (i < n4) {
    float4 v = ((const float4*)in)[i];
    ushort4 o;
    o.x = f2b(v.x); o.y = f2b(v.y); o.z = f2b(v.z); o.w = f2b(v.w);
    ((ushort4*)out)[i] = o;
  }
}

/* ---------------- RoPE cos/sin table: [SEQ][32] each ---------------- */
__global__ void rope_table_kernel(float* __restrict__ cs, float* __restrict__ sn) {
  int idx = blockIdx.x * blockDim.x + threadIdx.x;  /* l*32 + i, 65536 total */
  int i = idx & 31;
  int l = idx >> 5;
  float inv = powf(10000.0f, -((float)i) / 32.0f);
  float ang = (float)l * inv;
  cs[idx] = cosf(ang);
  sn[idx] = sinf(ang);
}

/* ---------------- NT GEMM: C[M,N] = A[M,K] * Bw[N,K]^T  (m97 structure) ----------------
   128x128 tile, BK=32, 256 threads (4 waves 2x2), global_load_lds staging. */
template<int OUTF>
__global__ __launch_bounds__(256)
void gemm_bt(const ushort* __restrict__ A, const ushort* __restrict__ Bw,
             void* __restrict__ Cv, int M, int N, int K) {
  __shared__ __align__(16) ushort As[128*32];
  __shared__ __align__(16) ushort Bs[128*32];
  const int tid  = threadIdx.x;
  const int wid  = tid >> 6;
  const int lane = tid & 63;
  const int wr   = wid >> 1, wc = wid & 1;
  const int l16  = lane & 15, lhi = lane >> 4;
  const int nb   = N >> 7;
  const int brow = (blockIdx.x / nb) << 7;
  const int bcol = (blockIdx.x % nb) << 7;

  f32x4 acc[4][4] = {};

  for (int k0 = 0; k0 < K; k0 += 32) {
    __syncthreads();   /* protect LDS from previous iteration's readers */
#pragma unroll
    for (int it = 0; it < 2; ++it) {
      const int cb    = (wid * 2 + it) * 64;      /* wave-uniform chunk base */
      const int chunk = cb + lane;
      const int r     = chunk >> 2;
      const int c8    = chunk & 3;
      const ushort* ga = A  + (size_t)(brow + r) * K + k0 + c8 * 8;
      const ushort* gb = Bw + (size_t)(bcol + r) * K + k0 + c8 * 8;
      __builtin_amdgcn_global_load_lds(
          (const __attribute__((address_space(1))) void*)ga,
          (__attribute__((address_space(3))) void*)(As + cb * 8), 16, 0, 0);
      __builtin_amdgcn_global_load_lds(
          (const __attribute__((address_space(1))) void*)gb,
          (__attribute__((address_space(3))) void*)(Bs + cb * 8), 16, 0, 0);
    }
    __syncthreads();   /* drains vmcnt(0): staged data visible */

    bf16x8 af[4], bfr[4];
#pragma unroll
    for (int m = 0; m < 4; ++m)
      af[m] = *(const bf16x8*)(As + (wr*64 + m*16 + l16)*32 + lhi*8);
#pragma unroll
    for (int n = 0; n < 4; ++n)
      bfr[n] = *(const bf16x8*)(Bs + (wc*64 + n*16 + l16)*32 + lhi*8);
#pragma unroll
    for (int m = 0; m < 4; ++m)
#pragma unroll
      for (int n = 0; n < 4; ++n)
        acc[m][n] = __builtin_amdgcn_mfma_f32_16x16x32_bf16(af[m], bfr[n], acc[m][n], 0, 0, 0);
  }

#pragma unroll
  for (int m = 0; m < 4; ++m)
#pragma unroll
    for (int n = 0; n < 4; ++n)
#pragma unroll
      for (int r = 0; r < 4; ++r) {
        const int row = brow + wr*64 + m*16 + lhi*4 + r;
        const int col = bcol + wc*64 + n*16 + l16;
        if (OUTF) ((float*)Cv)[(size_t)row * N + col] = acc[m][n][r];
        else      ((ushort*)Cv)[(size_t)row * N + col] = f2b(acc[m][n][r]);
      }
}

/* ---------------- RoPE: kqv(bf16)[4096][3072] -> Qb,Kb (b,h,L,64) bf16 ----------------
   thread per (bl, h, pair i): idx = ((bl)*16 + h)*32 + i */
__global__ void rope_kernel(const ushort* __restrict__ kqv,
                            const float* __restrict__ cs, const float* __restrict__ sn,
                            ushort* __restrict__ qb, ushort* __restrict__ kb) {
  int idx = blockIdx.x * blockDim.x + threadIdx.x;
  int i  = idx & 31;
  int h  = (idx >> 5) & 15;
  int bl = idx >> 9;                 /* 0..4095 */
  int l  = bl & (SEQ - 1);
  int b  = bl >> 11;
  float c = cs[l * 32 + i];
  float s = sn[l * 32 + i];
  size_t base = (size_t)bl * N3 + h * HDIM + 2 * i;
  uint32_t kp = *(const uint32_t*)(kqv + base);           /* K part: cols [0,1024) */
  uint32_t qp = *(const uint32_t*)(kqv + base + DMODEL);  /* Q part: cols [1024,2048) */
  float k1 = b2f((ushort)(kp & 0xffff)), k2 = b2f((ushort)(kp >> 16));
  float q1 = b2f((ushort)(qp & 0xffff)), q2 = b2f((ushort)(qp >> 16));
  float kr1 = k1 * c - k2 * s, kr2 = k1 * s + k2 * c;
  float qr1 = q1 * c - q2 * s, qr2 = q1 * s + q2 * c;
  size_t ob = ((size_t)(b * NHEADS + h) * SEQ + l) * HDIM + 2 * i;
  *(uint32_t*)(kb + ob) = (uint32_t)f2b(kr1) | ((uint32_t)f2b(kr2) << 16);
  *(uint32_t*)(qb + ob) = (uint32_t)f2b(qr1) | ((uint32_t)f2b(qr2) << 16);
}

/* ---------------- V transpose: kqv cols [2048,3072) -> Vt (b,h,64,L) bf16 ---------------- */
__global__ void vtrans_kernel(const ushort* __restrict__ kqv, ushort* __restrict__ vt) {
  __shared__ ushort tile[64][65];
  int bid = blockIdx.x;          /* bh*32 + lt */
  int lt = bid & 31, bh = bid >> 5;
  int b = bh >> 4, h = bh & 15;
  int tid = threadIdx.x;
  int r = tid >> 2, cq = tid & 3;
  size_t gbase = ((size_t)(b * SEQ + lt * 64 + r)) * N3 + 2 * DMODEL + h * HDIM + cq * 16;
#pragma unroll
  for (int j = 0; j < 16; ++j) tile[r][cq * 16 + j] = kqv[gbase + j];
  __syncthreads();
  int d = tid >> 2;
  size_t obase = ((size_t)(bh * HDIM + d)) * SEQ + lt * 64 + cq * 16;
#pragma unroll
  for (int j = 0; j < 16; ++j) vt[obase + j] = tile[cq * 16 + j][d];
}

/* ---------------- Flash attention, causal, d=64 ----------------
   block = (bh, qtile of 64 rows), 256 threads = 4 waves x 16 q-rows, KT=64.
   K/V frags straight from global (L2-resident); P bounced via wave-private LDS. */
__global__ __launch_bounds__(256)
void attn_kernel(const ushort* __restrict__ qb, const ushort* __restrict__ kb,
                 const ushort* __restrict__ vt, ushort* __restrict__ attn) {
  __shared__ __align__(16) ushort plds[4][16 * 64];
  int bid = blockIdx.x;
  int qt = bid & 31, bh = bid >> 5;
  int wid = threadIdx.x >> 6, lane = threadIdx.x & 63;
  int l16 = lane & 15, lhi = lane >> 4;
  int r0 = qt * 64 + wid * 16;

  const ushort* Q  = qb + (size_t)bh * SEQ * HDIM;
  const ushort* Kp = kb + (size_t)bh * SEQ * HDIM;
  const ushort* Vp = vt + (size_t)bh * HDIM * SEQ;

  bf16x8 qf[2];
#pragma unroll
  for (int kc = 0; kc < 2; ++kc)
    qf[kc] = *(const bf16x8*)(Q + (size_t)(r0 + l16) * HDIM + kc * 32 + lhi * 8);

  float m[4], lsum[4];
  f32x4 o[4] = {};
#pragma unroll
  for (int r = 0; r < 4; ++r) { m[r] = -1e30f; lsum[r] = 0.0f; }

  ushort* pw = &plds[wid][0];

  for (int kt = 0; kt <= qt; ++kt) {
    f32x4 s[4];
#pragma unroll
    for (int n = 0; n < 4; ++n) {
      bf16x8 kf0 = *(const bf16x8*)(Kp + (size_t)(kt*64 + n*16 + l16) * HDIM + 0*32 + lhi*8);
      bf16x8 kf1 = *(const bf16x8*)(Kp + (size_t)(kt*64 + n*16 + l16) * HDIM + 1*32 + lhi*8);
      f32x4 z = 0.0f;
      z = __builtin_amdgcn_mfma_f32_16x16x32_bf16(qf[0], kf0, z, 0, 0, 0);
      z = __builtin_amdgcn_mfma_f32_16x16x32_bf16(qf[1], kf1, z, 0, 0, 0);
      s[n] = z;
    }
    const bool diag = (kt == qt);
#pragma unroll
    for (int n = 0; n < 4; ++n)
#pragma unroll
      for (int r = 0; r < 4; ++r) {
        float v = s[n][r] * 0.125f;
        if (diag && (n*16 + l16 > wid*16 + lhi*4 + r)) v = -1e30f;
        s[n][r] = v;
      }
    float alpha[4];
#pragma unroll
    for (int r = 0; r < 4; ++r) {
      float pm = fmaxf(fmaxf(s[0][r], s[1][r]), fmaxf(s[2][r], s[3][r]));
      pm = fmaxf(pm, __shfl_xor(pm, 1, 16));
      pm = fmaxf(pm, __shfl_xor(pm, 2, 16));
      pm = fmaxf(pm, __shfl_xor(pm, 4, 16));
      pm = fmaxf(pm, __shfl_xor(pm, 8, 16));
      float nm = fmaxf(m[r], pm);
      alpha[r] = __expf(m[r] - nm);
      m[r] = nm;
    }
    float psum[4] = {0.f, 0.f, 0.f, 0.f};
#pragma unroll
    for (int n = 0; n < 4; ++n)
#pragma unroll
      for (int r = 0; r < 4; ++r) {
        float p = __expf(s[n][r] - m[r]);
        psum[r] += p;
        pw[(lhi*4 + r) * 64 + n*16 + l16] = f2b(p);
      }
#pragma unroll
    for (int r = 0; r < 4; ++r) {
      float ps = psum[r];
      ps += __shfl_xor(ps, 1, 16);
      ps += __shfl_xor(ps, 2, 16);
      ps += __shfl_xor(ps, 4, 16);
      ps += __shfl_xor(ps, 8, 16);
      lsum[r] = lsum[r] * alpha[r] + ps;
    }
#pragma unroll
    for (int f = 0; f < 4; ++f)
#pragma unroll
      for (int r = 0; r < 4; ++r)
        o[f][r] *= alpha[r];

    bf16x8 pa0 = *(const bf16x8*)(pw + l16 * 64 + 0*32 + lhi * 8);
    bf16x8 pa1 = *(const bf16x8*)(pw + l16 * 64 + 1*32 + lhi * 8);
#pragma unroll
    for (int f = 0; f < 4; ++f) {
      bf16x8 vf0 = *(const bf16x8*)(Vp + (size_t)(f*16 + l16) * SEQ + kt*64 + 0*32 + lhi*8);
      bf16x8 vf1 = *(const bf16x8*)(Vp + (size_t)(f*16 + l16) * SEQ + kt*64 + 1*32 + lhi*8);
      o[f] = __builtin_amdgcn_mfma_f32_16x16x32_bf16(pa0, vf0, o[f], 0, 0, 0);
      o[f] = __builtin_amdgcn_mfma_f32_16x16x32_bf16(pa1, vf1, o[f], 0, 0, 0);
    }
  }

  int b = bh >> 4, h = bh & 15;
#pragma unroll
  for (int r = 0; r < 4; ++r) {
    float inv = 1.0f / lsum[r];
    int qg = qt * 64 + wid * 16 + lhi * 4 + r;
    size_t base = ((size_t)(b * SEQ + qg)) * DMODEL + h * HDIM;
#pragma unroll
    for (int f = 0; f < 4; ++f)
      attn[base + f*16 + l16] = f2b(o[f][r] * inv);
  }
}

extern "C" void kernel_launch(void* const* d_in, const int* in_sizes, int n_in,
                              void* d_out, int out_size, void* d_ws, size_t ws_size,
                              hipStream_t stream) {
  const float* x    = (const float*)d_in[0];
  const float* wkqv = (const float*)d_in[1];
  const float* wo   = (const float*)d_in[2];
  float* out = (float*)d_out;

  /* ws layout (ushort units). attn result reuses xb's slot (dead after GEMM1). */
  ushort* xb   = (ushort*)d_ws;            /* 4096*1024  — later reused as attn out */
  ushort* wkb  = xb  + (size_t)MROWS * DMODEL;      /* 3072*1024 */
  ushort* wob  = wkb + (size_t)N3 * DMODEL;         /* 1024*1024 */
  ushort* kqv  = wob + (size_t)DMODEL * DMODEL;     /* 4096*3072 */
  ushort* qb   = kqv + (size_t)MROWS * N3;          /* 4096*1024 */
  ushort* kb   = qb  + (size_t)MROWS * DMODEL;      /* 4096*1024 */
  ushort* vt   = kb  + (size_t)MROWS * DMODEL;      /* 4096*1024 */
  float*  cs   = (float*)(vt + (size_t)MROWS * DMODEL);
  float*  sn   = cs + SEQ * 32;
  ushort* attn = xb;  /* alias: xb dead after GEMM1 */

  int nx = MROWS * DMODEL / 4, nw = N3 * DMODEL / 4, no = DMODEL * DMODEL / 4;
  f2b_kernel<<<nx / 256, 256, 0, stream>>>(x, xb, nx);
  f2b_kernel<<<nw / 256, 256, 0, stream>>>(wkqv, wkb, nw);
  f2b_kernel<<<no / 256, 256, 0, stream>>>(wo, wob, no);
  rope_table_kernel<<<SEQ * 32 / 256, 256, 0, stream>>>(cs, sn);

  gemm_bt<0><<<(MROWS/128) * (N3/128), 256, 0, stream>>>(xb, wkb, (void*)kqv, MROWS, N3, DMODEL);

  rope_kernel<<<(MROWS * NHEADS * 32) / 256, 256, 0, stream>>>(kqv, cs, sn, qb, kb);
  vtrans_kernel<<<BATCH * NHEADS * (SEQ / 64), 256, 0, stream>>>(kqv, vt);

  attn_kernel<<<BATCH * NHEADS * (SEQ / 64), 256, 0, stream>>>(qb, kb, vt, attn);

  gemm_bt<1><<<(MROWS/128) * (DMODEL/128), 256, 0, stream>>>(attn, wob, (void*)out, MROWS, DMODEL, DMODEL);
}

// Round 2
// 225.318 us; speedup vs baseline: 1.4106x; 1.4106x over previous
//
#include <hip/hip_runtime.h>
#include <hip/hip_bf16.h>
#include <stdint.h>

#define BATCH 2
#define SEQ 2048
#define DMODEL 1024
#define NHEADS 16
#define HDIM 64
#define MROWS (BATCH*SEQ)   /* 4096 */
#define N3 (3*DMODEL)       /* 3072 */

typedef __attribute__((ext_vector_type(8))) __bf16 bf16x8;
typedef __attribute__((ext_vector_type(4))) float f32x4;

__device__ __forceinline__ ushort f2b(float f) {
  uint32_t u = __builtin_bit_cast(uint32_t, f);
  uint32_t r = (u + 0x7FFFu + ((u >> 16) & 1u)) >> 16;
  return (ushort)r;
}
__device__ __forceinline__ float b2f(ushort h) {
  return __builtin_bit_cast(float, (uint32_t)h << 16);
}

/* ---------------- f32 -> bf16 convert, 4 elems/thread ---------------- */
__global__ void f2b_kernel(const float* __restrict__ in, ushort* __restrict__ out, int n4) {
  int i = blockIdx.x * blockDim.x + threadIdx.x;
  if (i < n4) {
    float4 v = ((const float4*)in)[i];
    ushort4 o;
    o.x = f2b(v.x); o.y = f2b(v.y); o.z = f2b(v.z); o.w = f2b(v.w);
    ((ushort4*)out)[i] = o;
  }
}

/* ---------------- RoPE cos/sin table: [SEQ][32] each ---------------- */
__global__ void rope_table_kernel(float* __restrict__ cs, float* __restrict__ sn) {
  int idx = blockIdx.x * blockDim.x + threadIdx.x;  /* l*32 + i, 65536 total */
  int i = idx & 31;
  int l = idx >> 5;
  float inv = powf(10000.0f, -((float)i) / 32.0f);
  float ang = (float)l * inv;
  cs[idx] = cosf(ang);
  sn[idx] = sinf(ang);
}

/* ---------------- NT GEMM: C[M,N] = A[M,K] * Bw[N,K]^T  (m97 structure) ----------------
   128x128 tile, BK=32, 256 threads (4 waves 2x2), global_load_lds staging. */
template<int OUTF>
__global__ __launch_bounds__(256)
void gemm_bt(const ushort* __restrict__ A, const ushort* __restrict__ Bw,
             void* __restrict__ Cv, int M, int N, int K) {
  __shared__ __align__(16) ushort As[128*32];
  __shared__ __align__(16) ushort Bs[128*32];
  const int tid  = threadIdx.x;
  const int wid  = tid >> 6;
  const int lane = tid & 63;
  const int wr   = wid >> 1, wc = wid & 1;
  const int l16  = lane & 15, lhi = lane >> 4;
  const int nb   = N >> 7;
  const int brow = (blockIdx.x / nb) << 7;
  const int bcol = (blockIdx.x % nb) << 7;

  f32x4 acc[4][4] = {};

  for (int k0 = 0; k0 < K; k0 += 32) {
    __syncthreads();   /* protect LDS from previous iteration's readers */
#pragma unroll
    for (int it = 0; it < 2; ++it) {
      const int cb    = (wid * 2 + it) * 64;      /* wave-uniform chunk base */
      const int chunk = cb + lane;
      const int r     = chunk >> 2;
      const int c8    = chunk & 3;
      const ushort* ga = A  + (size_t)(brow + r) * K + k0 + c8 * 8;
      const ushort* gb = Bw + (size_t)(bcol + r) * K + k0 + c8 * 8;
      __builtin_amdgcn_global_load_lds(
          (const __attribute__((address_space(1))) void*)ga,
          (__attribute__((address_space(3))) void*)(As + cb * 8), 16, 0, 0);
      __builtin_amdgcn_global_load_lds(
          (const __attribute__((address_space(1))) void*)gb,
          (__attribute__((address_space(3))) void*)(Bs + cb * 8), 16, 0, 0);
    }
    __syncthreads();   /* drains vmcnt(0): staged data visible */

    bf16x8 af[4], bfr[4];
#pragma unroll
    for (int m = 0; m < 4; ++m)
      af[m] = *(const bf16x8*)(As + (wr*64 + m*16 + l16)*32 + lhi*8);
#pragma unroll
    for (int n = 0; n < 4; ++n)
      bfr[n] = *(const bf16x8*)(Bs + (wc*64 + n*16 + l16)*32 + lhi*8);
#pragma unroll
    for (int m = 0; m < 4; ++m)
#pragma unroll
      for (int n = 0; n < 4; ++n)
        acc[m][n] = __builtin_amdgcn_mfma_f32_16x16x32_bf16(af[m], bfr[n], acc[m][n], 0, 0, 0);
  }

#pragma unroll
  for (int m = 0; m < 4; ++m)
#pragma unroll
    for (int n = 0; n < 4; ++n)
#pragma unroll
      for (int r = 0; r < 4; ++r) {
        const int row = brow + wr*64 + m*16 + lhi*4 + r;
        const int col = bcol + wc*64 + n*16 + l16;
        if (OUTF) ((float*)Cv)[(size_t)row * N + col] = acc[m][n][r];
        else      ((ushort*)Cv)[(size_t)row * N + col] = f2b(acc[m][n][r]);
      }
}

/* ---------------- RoPE: kqv(bf16)[4096][3072] -> Qb,Kb (b,h,L,64) bf16 ---------------- */
__global__ void rope_kernel(const ushort* __restrict__ kqv,
                            const float* __restrict__ cs, const float* __restrict__ sn,
                            ushort* __restrict__ qb, ushort* __restrict__ kb) {
  int idx = blockIdx.x * blockDim.x + threadIdx.x;
  int i  = idx & 31;
  int h  = (idx >> 5) & 15;
  int bl = idx >> 9;                 /* 0..4095 */
  int l  = bl & (SEQ - 1);
  int b  = bl >> 11;
  float c = cs[l * 32 + i];
  float s = sn[l * 32 + i];
  size_t base = (size_t)bl * N3 + h * HDIM + 2 * i;
  uint32_t kp = *(const uint32_t*)(kqv + base);           /* K part: cols [0,1024) */
  uint32_t qp = *(const uint32_t*)(kqv + base + DMODEL);  /* Q part: cols [1024,2048) */
  float k1 = b2f((ushort)(kp & 0xffff)), k2 = b2f((ushort)(kp >> 16));
  float q1 = b2f((ushort)(qp & 0xffff)), q2 = b2f((ushort)(qp >> 16));
  float kr1 = k1 * c - k2 * s, kr2 = k1 * s + k2 * c;
  float qr1 = q1 * c - q2 * s, qr2 = q1 * s + q2 * c;
  size_t ob = ((size_t)(b * NHEADS + h) * SEQ + l) * HDIM + 2 * i;
  *(uint32_t*)(kb + ob) = (uint32_t)f2b(kr1) | ((uint32_t)f2b(kr2) << 16);
  *(uint32_t*)(qb + ob) = (uint32_t)f2b(qr1) | ((uint32_t)f2b(qr2) << 16);
}

/* ---------------- V transpose: kqv cols [2048,3072) -> Vt (b,h,64,L) bf16 ---------------- */
__global__ void vtrans_kernel(const ushort* __restrict__ kqv, ushort* __restrict__ vt) {
  __shared__ ushort tile[64][65];
  int bid = blockIdx.x;          /* bh*32 + lt */
  int lt = bid & 31, bh = bid >> 5;
  int b = bh >> 4, h = bh & 15;
  int tid = threadIdx.x;
  int r = tid >> 2, cq = tid & 3;
  size_t gbase = ((size_t)(b * SEQ + lt * 64 + r)) * N3 + 2 * DMODEL + h * HDIM + cq * 16;
#pragma unroll
  for (int j = 0; j < 16; ++j) tile[r][cq * 16 + j] = kqv[gbase + j];
  __syncthreads();
  int d = tid >> 2;
  size_t obase = ((size_t)(bh * HDIM + d)) * SEQ + lt * 64 + cq * 16;
#pragma unroll
  for (int j = 0; j < 16; ++j) vt[obase + j] = tile[cq * 16 + j][d];
}

/* ---------------- Flash attention, causal, d=64 ----------------
   block = (bh, 64-row q-tile), 256 threads = 4 waves x 16 q-rows, KT=64.
   LPT remap: qt = 31 - (bid>>5), bh = bid&31  -> long blocks dispatch first,
   and XCD ~ bid%8 = bh%8 keeps each head's K/V in one XCD's L2.
   K double-buffered in registers (prefetch kt+1 during kt); V issued before
   softmax so its latency hides under softmax. */
__global__ __launch_bounds__(256)
void attn_kernel(const ushort* __restrict__ qb, const ushort* __restrict__ kb,
                 const ushort* __restrict__ vt, ushort* __restrict__ attn) {
  __shared__ __align__(16) ushort plds[4][16 * 64];
  int bid = blockIdx.x;
  int qt = 31 - (bid >> 5);
  int bh = bid & 31;
  int wid = threadIdx.x >> 6, lane = threadIdx.x & 63;
  int l16 = lane & 15, lhi = lane >> 4;
  int r0 = qt * 64 + wid * 16;

  const ushort* Q  = qb + (size_t)bh * SEQ * HDIM;
  const ushort* Kp = kb + (size_t)bh * SEQ * HDIM;
  const ushort* Vp = vt + (size_t)bh * HDIM * SEQ;

  bf16x8 qf[2];
#pragma unroll
  for (int kc = 0; kc < 2; ++kc)
    qf[kc] = *(const bf16x8*)(Q + (size_t)(r0 + l16) * HDIM + kc * 32 + lhi * 8);

  float m[4], lsum[4];
  f32x4 o[4] = {};
#pragma unroll
  for (int r = 0; r < 4; ++r) { m[r] = -1e30f; lsum[r] = 0.0f; }

  ushort* pw = &plds[wid][0];

  bf16x8 kA[4][2], kB[4][2];
#pragma unroll
  for (int n = 0; n < 4; ++n)
#pragma unroll
    for (int c = 0; c < 2; ++c)
      kA[n][c] = *(const bf16x8*)(Kp + (size_t)(n*16 + l16) * HDIM + c*32 + lhi*8);

  auto iter = [&](bf16x8 (&kc_)[4][2], bf16x8 (&kn_)[4][2], int kt) {
    /* QK^T with current K fragments */
    f32x4 s[4];
#pragma unroll
    for (int n = 0; n < 4; ++n) {
      f32x4 z = 0.0f;
      z = __builtin_amdgcn_mfma_f32_16x16x32_bf16(qf[0], kc_[n][0], z, 0, 0, 0);
      z = __builtin_amdgcn_mfma_f32_16x16x32_bf16(qf[1], kc_[n][1], z, 0, 0, 0);
      s[n] = z;
    }
    /* issue V loads for this kt (consumed after softmax ~500cy later) */
    bf16x8 vf[4][2];
#pragma unroll
    for (int f = 0; f < 4; ++f)
#pragma unroll
      for (int c = 0; c < 2; ++c)
        vf[f][c] = *(const bf16x8*)(Vp + (size_t)(f*16 + l16) * SEQ + kt*64 + c*32 + lhi*8);
    /* issue K prefetch for kt+1 (clamped; last iter re-reads kt harmlessly) */
    const int ktn = (kt < qt) ? kt + 1 : kt;
#pragma unroll
    for (int n = 0; n < 4; ++n)
#pragma unroll
      for (int c = 0; c < 2; ++c)
        kn_[n][c] = *(const bf16x8*)(Kp + (size_t)(ktn*64 + n*16 + l16) * HDIM + c*32 + lhi*8);

    const bool diag = (kt == qt);
#pragma unroll
    for (int n = 0; n < 4; ++n)
#pragma unroll
      for (int r = 0; r < 4; ++r) {
        float v = s[n][r] * 0.125f;
        if (diag && (n*16 + l16 > wid*16 + lhi*4 + r)) v = -1e30f;
        s[n][r] = v;
      }
    float alpha[4];
#pragma unroll
    for (int r = 0; r < 4; ++r) {
      float pm = fmaxf(fmaxf(s[0][r], s[1][r]), fmaxf(s[2][r], s[3][r]));
      pm = fmaxf(pm, __shfl_xor(pm, 1, 16));
      pm = fmaxf(pm, __shfl_xor(pm, 2, 16));
      pm = fmaxf(pm, __shfl_xor(pm, 4, 16));
      pm = fmaxf(pm, __shfl_xor(pm, 8, 16));
      float nm = fmaxf(m[r], pm);
      alpha[r] = __expf(m[r] - nm);
      m[r] = nm;
    }
    float psum[4] = {0.f, 0.f, 0.f, 0.f};
#pragma unroll
    for (int n = 0; n < 4; ++n)
#pragma unroll
      for (int r = 0; r < 4; ++r) {
        float p = __expf(s[n][r] - m[r]);
        psum[r] += p;
        pw[(lhi*4 + r) * 64 + n*16 + l16] = f2b(p);
      }
#pragma unroll
    for (int r = 0; r < 4; ++r) {
      float ps = psum[r];
      ps += __shfl_xor(ps, 1, 16);
      ps += __shfl_xor(ps, 2, 16);
      ps += __shfl_xor(ps, 4, 16);
      ps += __shfl_xor(ps, 8, 16);
      lsum[r] = lsum[r] * alpha[r] + ps;
    }
#pragma unroll
    for (int f = 0; f < 4; ++f)
#pragma unroll
      for (int r = 0; r < 4; ++r)
        o[f][r] *= alpha[r];

    bf16x8 pa0 = *(const bf16x8*)(pw + l16 * 64 + 0*32 + lhi * 8);
    bf16x8 pa1 = *(const bf16x8*)(pw + l16 * 64 + 1*32 + lhi * 8);
#pragma unroll
    for (int f = 0; f < 4; ++f) {
      o[f] = __builtin_amdgcn_mfma_f32_16x16x32_bf16(pa0, vf[f][0], o[f], 0, 0, 0);
      o[f] = __builtin_amdgcn_mfma_f32_16x16x32_bf16(pa1, vf[f][1], o[f], 0, 0, 0);
    }
  };

  int kt = 0;
  while (true) {
    iter(kA, kB, kt);
    if (++kt > qt) break;
    iter(kB, kA, kt);
    if (++kt > qt) break;
  }

  int b = bh >> 4, h = bh & 15;
#pragma unroll
  for (int r = 0; r < 4; ++r) {
    float inv = 1.0f / lsum[r];
    int qg = qt * 64 + wid * 16 + lhi * 4 + r;
    size_t base = ((size_t)(b * SEQ + qg)) * DMODEL + h * HDIM;
#pragma unroll
    for (int f = 0; f < 4; ++f)
      attn[base + f*16 + l16] = f2b(o[f][r] * inv);
  }
}

extern "C" void kernel_launch(void* const* d_in, const int* in_sizes, int n_in,
                              void* d_out, int out_size, void* d_ws, size_t ws_size,
                              hipStream_t stream) {
  const float* x    = (const float*)d_in[0];
  const float* wkqv = (const float*)d_in[1];
  const float* wo   = (const float*)d_in[2];
  float* out = (float*)d_out;

  ushort* xb   = (ushort*)d_ws;                     /* 4096*1024 — reused as attn out */
  ushort* wkb  = xb  + (size_t)MROWS * DMODEL;      /* 3072*1024 */
  ushort* wob  = wkb + (size_t)N3 * DMODEL;         /* 1024*1024 */
  ushort* kqv  = wob + (size_t)DMODEL * DMODEL;     /* 4096*3072 */
  ushort* qb   = kqv + (size_t)MROWS * N3;          /* 4096*1024 */
  ushort* kb   = qb  + (size_t)MROWS * DMODEL;      /* 4096*1024 */
  ushort* vt   = kb  + (size_t)MROWS * DMODEL;      /* 4096*1024 */
  float*  cs   = (float*)(vt + (size_t)MROWS * DMODEL);
  float*  sn   = cs + SEQ * 32;
  ushort* attn = xb;  /* alias: xb dead after GEMM1 */

  int nx = MROWS * DMODEL / 4, nw = N3 * DMODEL / 4, no = DMODEL * DMODEL / 4;
  f2b_kernel<<<nx / 256, 256, 0, stream>>>(x, xb, nx);
  f2b_kernel<<<nw / 256, 256, 0, stream>>>(wkqv, wkb, nw);
  f2b_kernel<<<no / 256, 256, 0, stream>>>(wo, wob, no);
  rope_table_kernel<<<SEQ * 32 / 256, 256, 0, stream>>>(cs, sn);

  gemm_bt<0><<<(MROWS/128) * (N3/128), 256, 0, stream>>>(xb, wkb, (void*)kqv, MROWS, N3, DMODEL);

  rope_kernel<<<(MROWS * NHEADS * 32) / 256, 256, 0, stream>>>(kqv, cs, sn, qb, kb);
  vtrans_kernel<<<BATCH * NHEADS * (SEQ / 64), 256, 0, stream>>>(kqv, vt);

  attn_kernel<<<BATCH * NHEADS * (SEQ / 64), 256, 0, stream>>>(qb, kb, vt, attn);

  gemm_bt<1><<<(MROWS/128) * (DMODEL/128), 256, 0, stream>>>(attn, wob, (void*)out, MROWS, DMODEL, DMODEL);
}